// Round 1
// baseline (48831.863 us; speedup 1.0000x reference)
//
#include <hip/hip_runtime.h>
#include <math.h>

// Problem constants
#define BATCH 128
#define TT 800
#define SL 64          // sent_max_len L
#define AA 60          // alphabet
#define HH 400         // hidden
#define KK 10          // mixture components
#define MB 16          // batch per group
#define NG 8           // groups (NG*MB == BATCH)
#define NGATE 16       // gate WGs per group
#define NWPG 17        // WGs per group = NGATE + 1 window WG
#define UPW 25         // hidden units per gate WG (NGATE*UPW == HH)
#define NTHR 512

// d_out offsets (flat fp32, reference return order)
#define O_HF   (BATCH*TT*HH)
#define O_CF   (O_HF + BATCH*HH)
#define O_WIN  (O_CF + BATCH*HH)
#define O_WF   (O_WIN + BATCH*TT*AA)
#define O_KF   (O_WF + BATCH*AA)
#define O_PHI  (O_KF + BATCH*KK)

// ws layout (floats): [0..7]=cnt(int), [8..15]=wflag(int),
// 16: h_ws [NG][2][HH][MB], then w_ws [NG][AA][MB]

__device__ __forceinline__ float gld(const float* p) {
  return __hip_atomic_load(p, __ATOMIC_RELAXED, __HIP_MEMORY_SCOPE_AGENT);
}
__device__ __forceinline__ void gst(float* p, float v) {
  __hip_atomic_store(p, v, __ATOMIC_RELAXED, __HIP_MEMORY_SCOPE_AGENT);
}
// spin with bail-out so a sync bug fails visibly instead of hanging
__device__ __forceinline__ int spin_ge(int* p, int target) {
  for (int it = 0; it < (1 << 22); ++it) {
    if (__hip_atomic_load(p, __ATOMIC_ACQUIRE, __HIP_MEMORY_SCOPE_AGENT) >= target)
      return 1;
  }
  return 0;
}

__global__ void init_ws(int* wsi) {
  if (threadIdx.x < 16) wsi[threadIdx.x] = 0;
}

__global__ __launch_bounds__(NTHR) void lstm_persist(
    const float* __restrict__ strks, const float* __restrict__ onehots,
    const float* __restrict__ sents_m, const float* __restrict__ w_prev,
    const float* __restrict__ k_prev, const float* __restrict__ h0,
    const float* __restrict__ c0,
    const float* __restrict__ W_ih, const float* __restrict__ b_ih,
    const float* __restrict__ W_hh, const float* __restrict__ b_hh,
    const float* __restrict__ Wp, const float* __restrict__ bp,
    float* __restrict__ out, float* ws)
{
  const int g   = blockIdx.x / NWPG;
  const int wg  = blockIdx.x % NWPG;
  const int tid = threadIdx.x;
  const int b0  = g * MB;
  int* cnt   = ((int*)ws) + g;
  int* wflag = ((int*)ws) + 8 + g;
  float* hws = ws + 16 + g * (2*HH*MB);
  float* wws = ws + 16 + NG*(2*HH*MB) + g*(AA*MB);

  __shared__ float hbuf[HH*MB];        // [r][b]
  __shared__ float wbuf[AA*MB];        // [a][b]
  __shared__ float pbuf[3*KK*MB];      // [j][b]
  __shared__ float kbuf[KK*MB], abuf[KK*MB], bbuf[KK*MB];
  __shared__ float phibuf[(SL+1)*MB];  // [u][b]
  __shared__ float scalebuf[MB];
  __shared__ int s_ok;

  if (wg < NGATE) {
    // ---------------- gate workgroup: 25 hidden units x 16 batch ----------
    const int b  = tid & 15, ul = tid >> 4;   // ul in [0,32)
    const int u0 = wg * UPW;
    const bool act = (ul < UPW);
    const int unit = u0 + ul;
    float creg = 0.f;
    const float *wip0 = W_ih, *wip1 = W_ih, *wip2 = W_ih, *wip3 = W_ih;
    if (act) {
      creg = c0[(size_t)(b0+b)*HH + unit];
      wip0 = W_ih + (size_t)(unit)*63;
      wip1 = W_ih + (size_t)(HH+unit)*63;
      wip2 = W_ih + (size_t)(2*HH+unit)*63;
      wip3 = W_ih + (size_t)(3*HH+unit)*63;
    }
    for (int t = 0; t < TT; ++t) {
      // stage h_{t-1} (and w_prev at t==0) into LDS, transposed [r][b]
      if (t == 0) {
        for (int i = tid; i < HH*MB; i += NTHR)
          hbuf[i] = h0[(size_t)(b0+(i&15))*HH + (i>>4)];
        for (int i = tid; i < AA*MB; i += NTHR)
          wbuf[i] = w_prev[(size_t)(b0+(i&15))*AA + (i>>4)];
      } else {
        const float* src = hws + ((t&1)^1)*(HH*MB);
        for (int i = tid; i < HH*MB; i += NTHR) hbuf[i] = gld(src + i);
      }
      __syncthreads();

      float acc0=0.f, acc1=0.f, acc2=0.f, acc3=0.f;
      if (act) {
        acc0 = b_ih[unit]      + b_hh[unit];
        acc1 = b_ih[HH+unit]   + b_hh[HH+unit];
        acc2 = b_ih[2*HH+unit] + b_hh[2*HH+unit];
        acc3 = b_ih[3*HH+unit] + b_hh[3*HH+unit];
        const float* xs = strks + (size_t)(b0+b)*(TT*3) + t*3;
        float x0 = xs[0], x1 = xs[1], x2 = xs[2];
        acc0 += x0*wip0[0]+x1*wip0[1]+x2*wip0[2];
        acc1 += x0*wip1[0]+x1*wip1[1]+x2*wip1[2];
        acc2 += x0*wip2[0]+x1*wip2[1]+x2*wip2[2];
        acc3 += x0*wip3[0]+x1*wip3[1]+x2*wip3[2];
        const float* whp0 = W_hh + (size_t)(unit)*HH;
        const float* whp1 = W_hh + (size_t)(HH+unit)*HH;
        const float* whp2 = W_hh + (size_t)(2*HH+unit)*HH;
        const float* whp3 = W_hh + (size_t)(3*HH+unit)*HH;
        #pragma unroll 2
        for (int r = 0; r < HH; r += 4) {        // h-part first: overlaps window-WG latency
          float hv0=hbuf[r*MB+b],     hv1=hbuf[(r+1)*MB+b],
                hv2=hbuf[(r+2)*MB+b], hv3=hbuf[(r+3)*MB+b];
          float4 w0=*(const float4*)(whp0+r), w1=*(const float4*)(whp1+r),
                 w2=*(const float4*)(whp2+r), w3=*(const float4*)(whp3+r);
          acc0 += hv0*w0.x+hv1*w0.y+hv2*w0.z+hv3*w0.w;
          acc1 += hv0*w1.x+hv1*w1.y+hv2*w1.z+hv3*w1.w;
          acc2 += hv0*w2.x+hv1*w2.y+hv2*w2.z+hv3*w2.w;
          acc3 += hv0*w3.x+hv1*w3.y+hv2*w3.z+hv3*w3.w;
        }
      }
      if (t > 0) {                               // now wait for w_{t-1}
        if (tid == 0) s_ok = spin_ge(wflag, t);
        __syncthreads();
        if (!s_ok) return;
        for (int i = tid; i < AA*MB; i += NTHR) wbuf[i] = gld(wws + i);
        __syncthreads();
      }
      if (act) {
        #pragma unroll 4
        for (int k = 0; k < AA; ++k) {
          float wv = wbuf[k*MB+b];
          acc0 += wv*wip0[3+k]; acc1 += wv*wip1[3+k];
          acc2 += wv*wip2[3+k]; acc3 += wv*wip3[3+k];
        }
        float iv = 1.f/(1.f+expf(-acc0));
        float fv = 1.f/(1.f+expf(-acc1));
        float gv = tanhf(acc2);
        float ov = 1.f/(1.f+expf(-acc3));
        creg = fv*creg + iv*gv;
        float hv = ov*tanhf(creg);
        gst(hws + (t&1)*(HH*MB) + unit*MB + b, hv);
        out[(size_t)(b0+b)*(TT*HH) + (size_t)t*HH + unit] = hv;
        if (t == TT-1) {
          out[O_HF + (size_t)(b0+b)*HH + unit] = hv;
          out[O_CF + (size_t)(b0+b)*HH + unit] = creg;
        }
      }
      __threadfence();
      __syncthreads();
      if (tid == 0) __hip_atomic_fetch_add(cnt, 1, __ATOMIC_RELEASE, __HIP_MEMORY_SCOPE_AGENT);
      if (t < TT-1) {
        if (tid == 0) s_ok = spin_ge(cnt, NWPG*(t+1));
        __syncthreads();
        if (!s_ok) return;
      }
    }
  } else {
    // ---------------- window workgroup -----------------------------------
    for (int i = tid; i < KK*MB; i += NTHR)
      kbuf[i] = k_prev[(size_t)(b0+(i&15))*KK + (i>>4)];
    if (tid < MB) {
      float s = 0.f;
      for (int l = 0; l < SL; ++l) s += sents_m[(size_t)(b0+tid)*SL + l];
      scalebuf[tid] = (float)SL / s;
    }
    __syncthreads();
    for (int t = 0; t < TT; ++t) {
      __threadfence();
      __syncthreads();
      if (tid == 0) {
        __hip_atomic_fetch_add(cnt, 1, __ATOMIC_RELEASE, __HIP_MEMORY_SCOPE_AGENT);
        s_ok = spin_ge(cnt, NWPG*(t+1));         // wait for all h_t published
      }
      __syncthreads();
      if (!s_ok) return;
      const float* src = hws + (t&1)*(HH*MB);
      for (int i = tid; i < HH*MB; i += NTHR) hbuf[i] = gld(src + i);
      __syncthreads();
      // p = h @ Wp^T + bp   (30 x 16 dots of 400)
      if (tid < 3*KK*MB) {
        const int b = tid & 15, j = tid >> 4;
        const float* wp = Wp + (size_t)j*HH;
        float s = bp[j];
        for (int r = 0; r < HH; r += 4)
          s += hbuf[r*MB+b]*wp[r]     + hbuf[(r+1)*MB+b]*wp[r+1]
             + hbuf[(r+2)*MB+b]*wp[r+2] + hbuf[(r+3)*MB+b]*wp[r+3];
        pbuf[tid] = s;   // tid == j*16+b
      }
      __syncthreads();
      if (tid < KK*MB) {
        const int b = tid & 15, i = tid >> 4;
        abuf[tid] = expf(pbuf[i*MB+b]);
        bbuf[tid] = expf(pbuf[(KK+i)*MB+b]);
        kbuf[tid] = kbuf[tid] + expf(pbuf[(2*KK+i)*MB+b]);
      }
      __syncthreads();
      {
        const int b = tid & 15, u = tid >> 4;
        for (int uu = u; uu <= SL; uu += 32) {
          float s = 0.f;
          #pragma unroll
          for (int i = 0; i < KK; ++i) {
            float d = kbuf[i*MB+b] - (float)uu;
            s += abuf[i*MB+b]*expf(-bbuf[i*MB+b]*d*d);
          }
          s *= scalebuf[b];
          phibuf[uu*MB+b] = s;
          if (t == TT-1) out[O_PHI + (size_t)(b0+b)*(SL+1) + uu] = s;
        }
      }
      __syncthreads();
      {
        const int a0 = tid & 31, b = tid >> 5;   // lanes consecutive in alphabet dim
        for (int a = a0; a < AA; a += 32) {
          float s = 0.f;
          const float* oh = onehots + (size_t)(b0+b)*(SL*AA) + a;
          #pragma unroll 4
          for (int l = 0; l < SL; ++l) s += phibuf[l*MB+b]*oh[(size_t)l*AA];
          gst(wws + a*MB + b, s);
          out[O_WIN + (size_t)(b0+b)*(TT*AA) + (size_t)t*AA + a] = s;
          if (t == TT-1) out[O_WF + (size_t)(b0+b)*AA + a] = s;
        }
      }
      __threadfence();
      __syncthreads();
      if (tid == 0)
        __hip_atomic_store(wflag, t+1, __ATOMIC_RELEASE, __HIP_MEMORY_SCOPE_AGENT);
    }
    if (tid < KK*MB) {
      const int b = tid & 15, i = tid >> 4;
      out[O_KF + (size_t)(b0+b)*KK + i] = kbuf[i*MB+b];
    }
  }
}

extern "C" void kernel_launch(void* const* d_in, const int* in_sizes, int n_in,
                              void* d_out, int out_size, void* d_ws, size_t ws_size,
                              hipStream_t stream) {
  const float* strks   = (const float*)d_in[0];
  const float* onehots = (const float*)d_in[1];
  const float* sents_m = (const float*)d_in[2];
  const float* w_prev  = (const float*)d_in[3];
  const float* k_prev  = (const float*)d_in[4];
  const float* h0      = (const float*)d_in[5];
  const float* c0      = (const float*)d_in[6];
  const float* W_ih    = (const float*)d_in[7];
  const float* b_ih    = (const float*)d_in[8];
  const float* W_hh    = (const float*)d_in[9];
  const float* b_hh    = (const float*)d_in[10];
  const float* Wp      = (const float*)d_in[11];
  const float* bp      = (const float*)d_in[12];
  float* out = (float*)d_out;
  float* ws  = (float*)d_ws;
  hipLaunchKernelGGL(init_ws, dim3(1), dim3(64), 0, stream, (int*)d_ws);
  hipLaunchKernelGGL(lstm_persist, dim3(NG*NWPG), dim3(NTHR), 0, stream,
                     strks, onehots, sents_m, w_prev, k_prev, h0, c0,
                     W_ih, b_ih, W_hh, b_hh, Wp, bp, out, ws);
}